// Round 1
// baseline (475.130 us; speedup 1.0000x reference)
//
#include <hip/hip_runtime.h>

typedef __bf16 bf16;
typedef __bf16 bf16x8 __attribute__((ext_vector_type(8)));
typedef float f32x4 __attribute__((ext_vector_type(4)));

#define HH 128
#define WW 128
#define HP 130   // padded (xp) extent
#define NB 4
#define NC 64

// ---------------------------------------------------------------------------
// Kernel 1: pad+transpose  [b][ci][y][x] f32  ->  [b][y+1][x+1][ci] bf16
// interior only; ring pre-zeroed by hipMemsetAsync.
// ---------------------------------------------------------------------------
__global__ __launch_bounds__(256) void transpose_pad(const float* __restrict__ in,
                                                     bf16* __restrict__ out) {
  __shared__ float tile[64][65];
  const int b = blockIdx.z, y = blockIdx.y, x0 = blockIdx.x * 64;
  const int tid = threadIdx.x;
#pragma unroll
  for (int pass = 0; pass < 16; ++pass) {
    int ci = pass * 4 + (tid >> 6);
    int x = tid & 63;
    tile[ci][x] = in[((b * 64 + ci) * HH + y) * WW + x0 + x];
  }
  __syncthreads();
#pragma unroll
  for (int pass = 0; pass < 16; ++pass) {
    int x = pass * 4 + (tid >> 6);
    int ci = tid & 63;
    out[((size_t)(b * HP + (y + 1)) * HP + (x0 + x + 1)) * 64 + ci] = (bf16)tile[ci][x];
  }
}

// ---------------------------------------------------------------------------
// Kernel 2: pack conv weights into B-fragment layout.
// dst[ntile][kc(18)][lane(64)][8] bf16 ; element j: B[k][n], k=kc*32+(lane>>4)*8+j,
// n=ntile*16+(lane&15); k = tap*64 + ci ; W layout [n][ci][3][3].
// ---------------------------------------------------------------------------
__global__ void build_bfrag(const float* __restrict__ W1, int n1,
                            const float* __restrict__ W2, int n2,
                            bf16* __restrict__ dst, int ntiles) {
  int idx = blockIdx.x * 256 + threadIdx.x;
  int total = ntiles * 18 * 64;
  if (idx >= total) return;
  int lane = idx & 63;
  int kc = (idx >> 6) % 18;
  int nt = idx / (64 * 18);
  int n = nt * 16 + (lane & 15);
  int q = lane >> 4;
  bf16x8 v;
#pragma unroll
  for (int j = 0; j < 8; ++j) {
    int k = kc * 32 + q * 8 + j;
    int tap = k >> 6, ci = k & 63;
    float w = 0.f;
    if (n < n1) w = W1[(n * 64 + ci) * 9 + tap];
    else if (n < n1 + n2) w = W2[((n - n1) * 64 + ci) * 9 + tap];
    v[j] = (bf16)w;
  }
  *reinterpret_cast<bf16x8*>(dst + (size_t)idx * 8) = v;
}

// ---------------------------------------------------------------------------
// GEMM core: 8x8 pixel tile (M=64, 4 waves = 4 M-strips of 16), NT N-tiles of 16.
// A from padded-transposed input via LDS patch (10x10 pixels x 32 ci, stride 40),
// B frags straight from global (L2-resident). K = 9 taps * 64 ci, chunked 32.
// ---------------------------------------------------------------------------
template <int NT>
__device__ __forceinline__ void gemm_core(const bf16* __restrict__ At,
                                          const bf16* __restrict__ BfBase,
                                          int b, int h0, int w0,
                                          f32x4* acc, ushort* apatch) {
  const int tid = threadIdx.x;
  const int lane = tid & 63;
  const int wv = tid >> 6;
  const int q = lane >> 4;
  const int m = wv * 16 + (lane & 15);
  const int yy = m >> 3, xx = m & 7;
  const ushort* Atu = reinterpret_cast<const ushort*>(At);

  for (int half = 0; half < 2; ++half) {
    __syncthreads();
#pragma unroll
    for (int it = 0; it < 4; ++it) {
      int flat = tid + it * 256;
      if (flat < 800) {
        int c4 = flat & 7;        // group of 4 ci
        int p = flat >> 3;        // pixel 0..99
        int py = p / 10, px = p - py * 10;
        ushort4 v = *reinterpret_cast<const ushort4*>(
            Atu + ((size_t)((b * HP + h0 + py) * HP + (w0 + px))) * 64 + half * 32 + c4 * 4);
        *reinterpret_cast<ushort4*>(apatch + p * 40 + c4 * 4) = v;
      }
    }
    __syncthreads();
#pragma unroll
    for (int tap = 0; tap < 9; ++tap) {
      int dh = tap / 3, dw = tap - dh * 3;   // 0..2 (conv offset -1 folded into patch origin)
      int p = (yy + dh) * 10 + (xx + dw);
      bf16x8 a = *reinterpret_cast<const bf16x8*>(
          reinterpret_cast<const bf16*>(apatch) + p * 40 + q * 8);
      int kc = tap * 2 + half;
      const bf16* bptr = BfBase + (size_t)kc * 512 + lane * 8;
#pragma unroll
      for (int nt = 0; nt < NT; ++nt) {
        bf16x8 bb = *reinterpret_cast<const bf16x8*>(bptr + (size_t)nt * 9216);
        acc[nt] = __builtin_amdgcn_mfma_f32_16x16x32_bf16(a, bb, acc[nt], 0, 0, 0);
      }
    }
  }
}

// ---------------------------------------------------------------------------
// Kernel 3: offset(18) + mask(9, sigmoid) conv from feature_size.
// ---------------------------------------------------------------------------
__global__ __launch_bounds__(256) void conv_offm(const bf16* __restrict__ fs_t,
                                                 const bf16* __restrict__ Bf2,
                                                 const float* __restrict__ pb,
                                                 const float* __restrict__ mb,
                                                 float* __restrict__ off_buf,
                                                 float* __restrict__ m_buf) {
  __shared__ ushort apatch[100 * 40];
  const int tileid = blockIdx.x;
  const int b = tileid >> 8;
  const int t = tileid & 255;
  const int h0 = (t >> 4) * 8, w0 = (t & 15) * 8;
  f32x4 acc[2];
#pragma unroll
  for (int i = 0; i < 2; ++i) acc[i] = (f32x4){0.f, 0.f, 0.f, 0.f};
  gemm_core<2>(fs_t, Bf2, b, h0, w0, acc, apatch);

  const int lane = threadIdx.x & 63, wv = threadIdx.x >> 6;
  const int q = lane >> 4, l15 = lane & 15;
#pragma unroll
  for (int nt = 0; nt < 2; ++nt) {
    int n = nt * 16 + l15;
#pragma unroll
    for (int r = 0; r < 4; ++r) {
      int pm = wv * 16 + q * 4 + r;
      int h = h0 + (pm >> 3), w = w0 + (pm & 7);
      float v = acc[nt][r];
      if (n < 18) {
        off_buf[((b * 18 + n) * HH + h) * WW + w] = v + pb[n];
      } else if (n < 27) {
        float z = v + mb[n - 18];
        m_buf[((b * 9 + (n - 18)) * HH + h) * WW + w] = 1.f / (1.f + __expf(-z));
      }
    }
  }
}

// ---------------------------------------------------------------------------
// Kernel 4: fused PSF conv (GEMM, N=144 chunk = 16 channels x 9 taps) + deformable
// bilinear sampling + dynamic-filter reduction.
// grid = (1024 pixel tiles, 4 channel chunks)
// ---------------------------------------------------------------------------
__global__ __launch_bounds__(256) void fused_main(const bf16* __restrict__ ctx_t,
                                                  const bf16* __restrict__ Bf,
                                                  const float* __restrict__ fb,
                                                  const float* __restrict__ x,
                                                  const float* __restrict__ off_buf,
                                                  const float* __restrict__ m_buf,
                                                  float* __restrict__ out) {
  __shared__ float Psm[64 * 148];           // also aliased as A-patch during GEMM
  ushort* apatch = (ushort*)Psm;

  const int tileid = blockIdx.x;
  const int cc = blockIdx.y;                // channel chunk: channels [cc*16, cc*16+16)
  const int b = tileid >> 8;
  const int t = tileid & 255;
  const int h0 = (t >> 4) * 8, w0 = (t & 15) * 8;

  f32x4 acc[9];
#pragma unroll
  for (int i = 0; i < 9; ++i) acc[i] = (f32x4){0.f, 0.f, 0.f, 0.f};
  gemm_core<9>(ctx_t, Bf + (size_t)cc * 9 * 9216, b, h0, w0, acc, apatch);
  __syncthreads();   // A-patch reads done before overwriting smem with P

  // P (+bias) -> LDS, layout [m][148] (padded: 2-way max bank conflict)
  {
    const int lane = threadIdx.x & 63, wv = threadIdx.x >> 6;
    const int q = lane >> 4, l15 = lane & 15;
#pragma unroll
    for (int nt = 0; nt < 9; ++nt) {
      int nl = nt * 16 + l15;
      float bias = fb[cc * 144 + nl];
#pragma unroll
      for (int r = 0; r < 4; ++r) {
        int pm = wv * 16 + q * 4 + r;
        Psm[pm * 148 + nl] = acc[nt][r] + bias;
      }
    }
  }
  __syncthreads();

  // Phase 2: thread = (pixel pm = tid&63, channel group cg = tid>>6 -> 4 channels)
  const int pm = threadIdx.x & 63;
  const int cg = threadIdx.x >> 6;
  const int h = h0 + (pm >> 3), w = w0 + (pm & 7);
  float res[4] = {0.f, 0.f, 0.f, 0.f};
  const float* xb = x + (size_t)b * 64 * (HH * WW);

#pragma unroll
  for (int i3 = 0; i3 < 3; ++i3) {
#pragma unroll
    for (int j3 = 0; j3 < 3; ++j3) {
      const int dh = (i3 == 0) ? -1 : 0, ri = (i3 == 0) ? 2 : (i3 - 1);
      const int dw = (j3 == 0) ? -1 : 0, rj = (j3 == 0) ? 2 : (j3 - 1);
      const int hh = h + dh, ww2 = w + dw;
      if (hh < 0 || ww2 < 0) continue;       // zero-pad of the shifted grid
      const int np = ri * 3 + rj;
      const int pixoff = hh * WW + ww2;
      float ox = off_buf[(b * 18 + np) * (HH * WW) + pixoff];
      float oy = off_buf[(b * 18 + 9 + np) * (HH * WW) + pixoff];
      float mv = m_buf[(b * 9 + np) * (HH * WW) + pixoff];
      // sampling position in xp coords (xp = x padded by 1, extent 130)
      float px = (float)(hh + 1) + (float)(ri - 1) + ox;
      float py = (float)(ww2 + 1) + (float)(rj - 1) + oy;
      float fx = floorf(px), fy = floorf(py);
      float ltx = fminf(fmaxf(fx, 0.f), 129.f);
      float lty = fminf(fmaxf(fy, 0.f), 129.f);
      float rbx = fminf(fmaxf(fx + 1.f, 0.f), 129.f);
      float rby = fminf(fmaxf(fy + 1.f, 0.f), 129.f);
      float pxc = fminf(fmaxf(px, 0.f), 129.f);
      float pyc = fminf(fmaxf(py, 0.f), 129.f);
      float glt = (1.f + ltx - pxc) * (1.f + lty - pyc);
      float grb = (1.f - rbx + pxc) * (1.f - rby + pyc);
      float glb = (1.f + ltx - pxc) * (1.f - rby + pyc);
      float grt = (1.f - rbx + pxc) * (1.f + lty - pyc);
      int ix0 = (int)ltx, iy0 = (int)lty, ix1 = (int)rbx, iy1 = (int)rby;
      // xp[i][j] = x[i-1][j-1] when 1<=i,j<=128 else 0
      float v00 = (ix0 >= 1 && ix0 <= 128 && iy0 >= 1 && iy0 <= 128) ? 1.f : 0.f;
      float v11 = (ix1 >= 1 && ix1 <= 128 && iy1 >= 1 && iy1 <= 128) ? 1.f : 0.f;
      float v01 = (ix0 >= 1 && ix0 <= 128 && iy1 >= 1 && iy1 <= 128) ? 1.f : 0.f;
      float v10 = (ix1 >= 1 && ix1 <= 128 && iy0 >= 1 && iy0 <= 128) ? 1.f : 0.f;
      float wlt = glt * v00, wrb = grb * v11, wlb = glb * v01, wrt = grt * v10;
      int jx0 = min(max(ix0 - 1, 0), 127), jy0 = min(max(iy0 - 1, 0), 127);
      int jx1 = min(max(ix1 - 1, 0), 127), jy1 = min(max(iy1 - 1, 0), 127);
      int a00 = jx0 * WW + jy0, a01 = jx0 * WW + jy1;
      int a10 = jx1 * WW + jy0, a11 = jx1 * WW + jy1;
      const int t9 = i3 * 3 + j3;
#pragma unroll
      for (int i = 0; i < 4; ++i) {
        int c_l = cg * 4 + i;
        const float* xc = xb + (size_t)(cc * 16 + c_l) * (HH * WW);
        float s = wlt * xc[a00] + wrb * xc[a11] + wlb * xc[a01] + wrt * xc[a10];
        res[i] += Psm[pm * 148 + c_l * 9 + t9] * (s * mv);
      }
    }
  }
#pragma unroll
  for (int i = 0; i < 4; ++i) {
    int c_l = cg * 4 + i;
    out[((size_t)(b * 64 + cc * 16 + c_l) * HH + h) * WW + w] = res[i];
  }
}

// ---------------------------------------------------------------------------
extern "C" void kernel_launch(void* const* d_in, const int* in_sizes, int n_in,
                              void* d_out, int out_size, void* d_ws, size_t ws_size,
                              hipStream_t stream) {
  (void)in_sizes; (void)n_in; (void)out_size; (void)ws_size;
  const float* fs  = (const float*)d_in[0];
  const float* ctx = (const float*)d_in[1];
  const float* x   = (const float*)d_in[2];
  const float* pw  = (const float*)d_in[3];
  const float* pb  = (const float*)d_in[4];
  const float* fw  = (const float*)d_in[5];
  const float* fb  = (const float*)d_in[6];
  const float* mw  = (const float*)d_in[7];
  const float* mb  = (const float*)d_in[8];

  char* ws = (char*)d_ws;
  bf16* fs_t   = (bf16*)(ws);                  // 4*130*130*64*2 = 8,652,800
  bf16* ctx_t  = (bf16*)(ws + 8652800);        // 8,652,800
  bf16* Bf     = (bf16*)(ws + 17305600);       // 36*18*64*8*2 = 663,552
  bf16* Bf2    = (bf16*)(ws + 17969152);       // 2*18*64*8*2  = 36,864
  float* offb  = (float*)(ws + 18006016);      // 4*18*128*128*4 = 4,718,592
  float* mbuf  = (float*)(ws + 22724608);      // 4*9*128*128*4  = 2,359,296

  // zero the padded rings of fs_t/ctx_t (interiors overwritten by transpose_pad)
  hipMemsetAsync(ws, 0, 17305600, stream);

  transpose_pad<<<dim3(2, 128, 4), 256, 0, stream>>>(fs, fs_t);
  transpose_pad<<<dim3(2, 128, 4), 256, 0, stream>>>(ctx, ctx_t);
  build_bfrag<<<162, 256, 0, stream>>>(fw, 576, (const float*)nullptr, 0, Bf, 36);
  build_bfrag<<<9, 256, 0, stream>>>(pw, 18, mw, 9, Bf2, 2);
  conv_offm<<<1024, 256, 0, stream>>>(fs_t, Bf2, pb, mb, offb, mbuf);
  fused_main<<<dim3(1024, 4), 256, 0, stream>>>(ctx_t, Bf, fb, x, offb, mbuf, (float*)d_out);
}

// Round 2
// 326.090 us; speedup vs baseline: 1.4571x; 1.4571x over previous
//
#include <hip/hip_runtime.h>

typedef __bf16 bf16;
typedef __bf16 bf16x8 __attribute__((ext_vector_type(8)));
typedef unsigned short u16x8 __attribute__((ext_vector_type(8)));
typedef float f32x4 __attribute__((ext_vector_type(4)));

#define HH 128
#define WW 128
#define HP 130   // padded extent

// ---------------------------------------------------------------------------
// Pad+transpose  [b][ci][y][x] f32  ->  [b][y+1][x+1][ci] bf16 (ring pre-zeroed)
// ---------------------------------------------------------------------------
__global__ __launch_bounds__(256) void transpose_pad(const float* __restrict__ in,
                                                     bf16* __restrict__ out) {
  __shared__ float tile[64][65];
  const int b = blockIdx.z, y = blockIdx.y, x0 = blockIdx.x * 64;
  const int tid = threadIdx.x;
#pragma unroll
  for (int pass = 0; pass < 16; ++pass) {
    int ci = pass * 4 + (tid >> 6);
    int x = tid & 63;
    tile[ci][x] = in[((b * 64 + ci) * HH + y) * WW + x0 + x];
  }
  __syncthreads();
#pragma unroll
  for (int pass = 0; pass < 16; ++pass) {
    int x = pass * 4 + (tid >> 6);
    int ci = tid & 63;
    out[((size_t)(b * HP + (y + 1)) * HP + (x0 + x + 1)) * 64 + ci] = (bf16)tile[ci][x];
  }
}

// Same but f32 output (for the deformable-gather source xp)
__global__ __launch_bounds__(256) void transpose_pad_f32(const float* __restrict__ in,
                                                         float* __restrict__ out) {
  __shared__ float tile[64][65];
  const int b = blockIdx.z, y = blockIdx.y, x0 = blockIdx.x * 64;
  const int tid = threadIdx.x;
#pragma unroll
  for (int pass = 0; pass < 16; ++pass) {
    int ci = pass * 4 + (tid >> 6);
    int x = tid & 63;
    tile[ci][x] = in[((b * 64 + ci) * HH + y) * WW + x0 + x];
  }
  __syncthreads();
#pragma unroll
  for (int pass = 0; pass < 16; ++pass) {
    int x = pass * 4 + (tid >> 6);
    int ci = tid & 63;
    out[((size_t)(b * HP + (y + 1)) * HP + (x0 + x + 1)) * 64 + ci] = tile[ci][x];
  }
}

// ---------------------------------------------------------------------------
// Pack conv weights into MFMA B-fragment layout.
// dst[nt][kc(18)][lane(64)][8]; elem j: B[k][n], k=kc*32+(lane>>4)*8+j, n=nt*16+(lane&15)
// k = tap*64 + ci; W layout [n][ci][3][3].
// ---------------------------------------------------------------------------
__global__ void build_bfrag(const float* __restrict__ W1, int n1,
                            const float* __restrict__ W2, int n2,
                            bf16* __restrict__ dst, int ntiles) {
  int idx = blockIdx.x * 256 + threadIdx.x;
  int total = ntiles * 18 * 64;
  if (idx >= total) return;
  int lane = idx & 63;
  int kc = (idx >> 6) % 18;
  int n = (idx / (64 * 18)) * 16 + (lane & 15);
  int q = lane >> 4;
  bf16x8 v;
#pragma unroll
  for (int j = 0; j < 8; ++j) {
    int k = kc * 32 + q * 8 + j;
    int tap = k >> 6, ci = k & 63;
    float w = 0.f;
    if (n < n1) w = W1[(n * 64 + ci) * 9 + tap];
    else if (n < n1 + n2) w = W2[((n - n1) * 64 + ci) * 9 + tap];
    v[j] = (bf16)w;
  }
  *reinterpret_cast<bf16x8*>(dst + (size_t)idx * 8) = v;
}

// ---------------------------------------------------------------------------
// GEMM core, 16x16 pixel tile (M=256). 4 waves; wave wv owns rows {s*4+wv}.
// A: 18x18 px x 64ci bf16 in LDS, XOR-swizzled 16B chunks (conflict-balanced,
// 16B-aligned). B: fragment-packed global (L2-resident), each load feeds 4 MFMA.
// ---------------------------------------------------------------------------
template <int NT>
__device__ __forceinline__ void gemm16(const bf16* __restrict__ At,
                                       const bf16* __restrict__ BfBase,
                                       int b, int h0, int w0,
                                       f32x4 (&acc)[4][NT], ushort* apatch) {
  const int tid = threadIdx.x;
  const int lane = tid & 63;
  const int wv = tid >> 6;
  const int q = lane >> 4;
  const int col = lane & 15;
  const ushort* Atu = reinterpret_cast<const ushort*>(At);

  // stage 324 px x 128B, 16B chunks, chunk c8 stored at (c8 ^ (px&7))
#pragma unroll
  for (int it = 0; it < 11; ++it) {
    int flat = it * 256 + tid;
    if (flat < 2592) {
      int px = flat >> 3, c8 = flat & 7;
      int py = px / 18, pxx = px - py * 18;
      u16x8 v = *reinterpret_cast<const u16x8*>(
          Atu + ((size_t)((b * HP + h0 + py) * HP + (w0 + pxx))) * 64 + c8 * 8);
      *reinterpret_cast<u16x8*>(apatch + px * 64 + ((c8 ^ (px & 7)) * 8)) = v;
    }
  }
  __syncthreads();

  const bf16* bl = BfBase + lane * 8;
  for (int dh = 0; dh < 3; ++dh) {
#pragma unroll
    for (int dw = 0; dw < 3; ++dw) {
      const int tap = dh * 3 + dw;
      bf16x8 a[4][2];
#pragma unroll
      for (int s = 0; s < 4; ++s) {
        int p = (s * 4 + wv + dh) * 18 + (col + dw);
#pragma unroll
        for (int half = 0; half < 2; ++half) {
          int ch = (half * 4 + q) ^ (p & 7);
          a[s][half] = *reinterpret_cast<const bf16x8*>(
              reinterpret_cast<const bf16*>(apatch) + p * 64 + ch * 8);
        }
      }
#pragma unroll
      for (int half = 0; half < 2; ++half) {
        const bf16* bp = bl + (tap * 2 + half) * 512;
#pragma unroll
        for (int nt = 0; nt < NT; ++nt) {
          bf16x8 bb = *reinterpret_cast<const bf16x8*>(bp + (size_t)nt * 9216);
#pragma unroll
          for (int s = 0; s < 4; ++s)
            acc[s][nt] = __builtin_amdgcn_mfma_f32_16x16x32_bf16(a[s][half], bb, acc[s][nt], 0, 0, 0);
        }
      }
    }
  }
}

// ---------------------------------------------------------------------------
// offset(18) + mask(9, sigmoid) conv from feature_size. M=256 tile.
// ---------------------------------------------------------------------------
__global__ __launch_bounds__(256, 4) void conv_offm(const bf16* __restrict__ fs_t,
                                                    const bf16* __restrict__ Bf2,
                                                    const float* __restrict__ pb,
                                                    const float* __restrict__ mb,
                                                    float* __restrict__ off_buf,
                                                    float* __restrict__ m_buf) {
  __shared__ __align__(16) ushort apatch[324 * 64];
  const int bid = blockIdx.x;
  const int b = bid >> 6;
  const int t = bid & 63;
  const int h0 = (t >> 3) * 16, w0 = (t & 7) * 16;
  f32x4 acc[4][2];
#pragma unroll
  for (int s = 0; s < 4; ++s)
#pragma unroll
    for (int n = 0; n < 2; ++n) acc[s][n] = (f32x4){0.f, 0.f, 0.f, 0.f};
  gemm16<2>(fs_t, Bf2, b, h0, w0, acc, apatch);

  const int lane = threadIdx.x & 63, wv = threadIdx.x >> 6;
  const int q = lane >> 4, col = lane & 15;
#pragma unroll
  for (int s = 0; s < 4; ++s) {
    int h = h0 + s * 4 + wv;
#pragma unroll
    for (int nt = 0; nt < 2; ++nt) {
      int n = nt * 16 + col;
#pragma unroll
      for (int j = 0; j < 4; ++j) {
        int w = w0 + q * 4 + j;
        float v = acc[s][nt][j];
        if (n < 18) {
          off_buf[((b * 18 + n) * HH + h) * WW + w] = v + pb[n];
        } else if (n < 27) {
          float z = v + mb[n - 18];
          m_buf[((b * 9 + (n - 18)) * HH + h) * WW + w] = 1.f / (1.f + __expf(-z));
        }
      }
    }
  }
}

// ---------------------------------------------------------------------------
// Fused: PSF conv GEMM (N=144 chunk) + deformable bilinear sampling + 9-tap
// dynamic-filter reduce. 16x16 px tile, epilogue in 4 rounds of 64 px.
// ---------------------------------------------------------------------------
__global__ __launch_bounds__(256, 2) void fused_main(const bf16* __restrict__ ctx_t,
                                                     const bf16* __restrict__ Bf,
                                                     const float* __restrict__ fb,
                                                     const float* __restrict__ xp,
                                                     const float* __restrict__ off_buf,
                                                     const float* __restrict__ m_buf,
                                                     float* __restrict__ out) {
  __shared__ __align__(16) char smem[41472];   // apatch 41472B  >  Psm 37120B
  ushort* apatch = (ushort*)smem;
  float* Psm = (float*)smem;                   // [64 px][145]

  const int bid = blockIdx.x;
  const int cc = blockIdx.y;                   // channel chunk (16 ch, n in [cc*144, +144))
  const int b = bid >> 6;
  const int t = bid & 63;
  const int h0 = (t >> 3) * 16, w0 = (t & 7) * 16;

  f32x4 acc[4][9];
#pragma unroll
  for (int s = 0; s < 4; ++s)
#pragma unroll
    for (int n = 0; n < 9; ++n) acc[s][n] = (f32x4){0.f, 0.f, 0.f, 0.f};
  gemm16<9>(ctx_t, Bf + (size_t)cc * 9 * 9216, b, h0, w0, acc, apatch);

  const int tid = threadIdx.x;
  const int lane = tid & 63, wv = tid >> 6;
  const int q = lane >> 4, col = lane & 15;
  float biasv[9];
#pragma unroll
  for (int nt = 0; nt < 9; ++nt) biasv[nt] = fb[cc * 144 + nt * 16 + col];

  const int pm = tid & 63;
  const int cg = tid >> 6;                     // wave id -> 4 channels
  const float* xpb = xp + (size_t)b * (HP * HP * 64) + cc * 16 + cg * 4;

  for (int r = 0; r < 4; ++r) {
    __syncthreads();                           // apatch (r=0) / prev-round reads done
    // P(+bias) -> LDS for rows 4r..4r+3 ; this wave's strip s=r is local row wv
#pragma unroll
    for (int nt = 0; nt < 9; ++nt) {
      int nl = nt * 16 + col;
#pragma unroll
      for (int j = 0; j < 4; ++j)
        Psm[(wv * 16 + q * 4 + j) * 145 + nl] = acc[r][nt][j] + biasv[nt];
    }
    __syncthreads();

    const int h = h0 + r * 4 + (pm >> 4), w = w0 + (pm & 15);
    f32x4 res = (f32x4){0.f, 0.f, 0.f, 0.f};
#pragma unroll
    for (int i3 = 0; i3 < 3; ++i3) {
#pragma unroll
      for (int j3 = 0; j3 < 3; ++j3) {
        const int dh = (i3 == 0) ? -1 : 0, ri = (i3 == 0) ? 2 : (i3 - 1);
        const int dw = (j3 == 0) ? -1 : 0, rj = (j3 == 0) ? 2 : (j3 - 1);
        const int hh = h + dh, ww2 = w + dw;
        if (hh < 0 || ww2 < 0) continue;       // zero-pad of the shifted grid
        const int np = ri * 3 + rj;
        const int pixoff = hh * WW + ww2;
        float ox = off_buf[(b * 18 + np) * (HH * WW) + pixoff];
        float oy = off_buf[(b * 18 + 9 + np) * (HH * WW) + pixoff];
        float mv = m_buf[(b * 9 + np) * (HH * WW) + pixoff];
        float px = (float)(hh + ri) + ox;      // (hh+1)+(ri-1)
        float py = (float)(ww2 + rj) + oy;
        float fx = floorf(px), fy = floorf(py);
        float ltx = fminf(fmaxf(fx, 0.f), 129.f);
        float lty = fminf(fmaxf(fy, 0.f), 129.f);
        float rbx = fminf(fmaxf(fx + 1.f, 0.f), 129.f);
        float rby = fminf(fmaxf(fy + 1.f, 0.f), 129.f);
        float pxc = fminf(fmaxf(px, 0.f), 129.f);
        float pyc = fminf(fmaxf(py, 0.f), 129.f);
        float glt = (1.f + ltx - pxc) * (1.f + lty - pyc);
        float grb = (1.f - rbx + pxc) * (1.f - rby + pyc);
        float glb = (1.f + ltx - pxc) * (1.f - rby + pyc);
        float grt = (1.f - rbx + pxc) * (1.f + lty - pyc);
        int ix0 = (int)ltx, iy0 = (int)lty, ix1 = (int)rbx, iy1 = (int)rby;
        // xp already has the zero ring -> no validity masks needed
        f32x4 x_lt = *reinterpret_cast<const f32x4*>(xpb + (size_t)(ix0 * HP + iy0) * 64);
        f32x4 x_rb = *reinterpret_cast<const f32x4*>(xpb + (size_t)(ix1 * HP + iy1) * 64);
        f32x4 x_lb = *reinterpret_cast<const f32x4*>(xpb + (size_t)(ix0 * HP + iy1) * 64);
        f32x4 x_rt = *reinterpret_cast<const f32x4*>(xpb + (size_t)(ix1 * HP + iy0) * 64);
        f32x4 sv = glt * x_lt + grb * x_rb + glb * x_lb + grt * x_rt;
        const int t9 = i3 * 3 + j3;
#pragma unroll
        for (int i = 0; i < 4; ++i)
          res[i] += Psm[pm * 145 + (cg * 4 + i) * 9 + t9] * (sv[i] * mv);
      }
    }
#pragma unroll
    for (int i = 0; i < 4; ++i)
      out[((size_t)(b * 64 + cc * 16 + cg * 4 + i) * HH + h) * WW + w] = res[i];
  }
}

// ---------------------------------------------------------------------------
extern "C" void kernel_launch(void* const* d_in, const int* in_sizes, int n_in,
                              void* d_out, int out_size, void* d_ws, size_t ws_size,
                              hipStream_t stream) {
  (void)in_sizes; (void)n_in; (void)out_size; (void)ws_size;
  const float* fs  = (const float*)d_in[0];
  const float* ctx = (const float*)d_in[1];
  const float* x   = (const float*)d_in[2];
  const float* pw  = (const float*)d_in[3];
  const float* pb  = (const float*)d_in[4];
  const float* fw  = (const float*)d_in[5];
  const float* fb  = (const float*)d_in[6];
  const float* mw  = (const float*)d_in[7];
  const float* mb  = (const float*)d_in[8];

  char* ws = (char*)d_ws;
  bf16*  ctx_t = (bf16*)(ws);                   //  8,652,800
  bf16*  Bf    = (bf16*)(ws + 8652800);         //    663,552
  float* offb  = (float*)(ws + 9316352);        //  4,718,592
  float* mbuf  = (float*)(ws + 14034944);       //  2,359,296
  bf16*  Bf2   = (bf16*)(ws + 16394240);        //     36,864
  float* xp    = (float*)(ws + 16431104);       // 17,318,400 (4*130*130*64*4)
  bf16*  fs_t  = (bf16*)(ws + 16431104);        //  8,652,800 — overlaps xp; dead
                                                //  before xp is built (see order)

  // zero padded rings (interiors overwritten by transposes)
  hipMemsetAsync(ctx_t, 0, 8652800, stream);
  hipMemsetAsync((void*)fs_t, 0, 8652800, stream);

  transpose_pad<<<dim3(2, 128, 4), 256, 0, stream>>>(fs, fs_t);
  transpose_pad<<<dim3(2, 128, 4), 256, 0, stream>>>(ctx, ctx_t);
  build_bfrag<<<162, 256, 0, stream>>>(fw, 576, (const float*)nullptr, 0, Bf, 36);
  build_bfrag<<<9, 256, 0, stream>>>(pw, 18, mw, 9, Bf2, 2);
  conv_offm<<<256, 256, 0, stream>>>(fs_t, Bf2, pb, mb, offb, mbuf);
  // fs_t is dead now; build xp (f32, padded, channel-last) in its place
  hipMemsetAsync((void*)xp, 0, 17318400, stream);
  transpose_pad_f32<<<dim3(2, 128, 4), 256, 0, stream>>>(x, xp);
  fused_main<<<dim3(256, 4), 256, 0, stream>>>(ctx_t, Bf, fb, xp, offb, mbuf, (float*)d_out);
}